// Round 20
// baseline (180.912 us; speedup 1.0000x reference)
//
#include <hip/hip_runtime.h>
#include <hip/hip_bf16.h>
#include <math.h>

#define H 8
#define NSEQ 1024
#define D 64
#define DIMM 512
#define NSELK 8
#define SCALE 0.125f
#define FEPS 1.1920929e-07f
#define NEGINF (-__builtin_inff())

typedef _Float16 f16;
typedef _Float16 h2 __attribute__((ext_vector_type(2)));
__device__ __forceinline__ h2 as_h2(unsigned u) { return __builtin_bit_cast(h2, u); }

#if __has_builtin(__builtin_amdgcn_fdot2)
#define FDOT2(a, b, c) __builtin_amdgcn_fdot2((a), (b), (c), false)
#else
#define FDOT2(a, b, c) ((c) + (float)(a).x * (float)(b).x + (float)(a).y * (float)(b).y)
#endif

// ws offsets (in floats)
#define OFF_XN    0
#define OFF_Q     524288
#define OFF_K     1048576
#define OFF_V     1572864
#define OFF_FQ    2097152   // f16
#define OFF_FKB   2621440   // f16
#define OFF_SKB   2883584   // f16
#define OFF_SQ    3145728   // f16
#define OFF_VB    3670016   // f16
#define OFF_GATE  4194304
#define OFF_CK    4218880
#define OFF_CV    4237312
#define OFF_PRE   4255744

__device__ __forceinline__ float wave_max(float v) {
#pragma unroll
  for (int off = 32; off > 0; off >>= 1) v = fmaxf(v, __shfl_xor(v, off));
  return v;
}
__device__ __forceinline__ float wave_sum(float v) {
#pragma unroll
  for (int off = 32; off > 0; off >>= 1) v += __shfl_xor(v, off);
  return v;
}

// ---------------- RMSNorm + fused gate projection ----------------
__global__ __launch_bounds__(256) void k_rmsnorm(const float* __restrict__ inp,
                                                 const float* __restrict__ g,
                                                 const float* __restrict__ wg,
                                                 const float* __restrict__ bg,
                                                 float* __restrict__ xn,
                                                 float* __restrict__ gate) {
  int row = blockIdx.x;
  __shared__ float xs[512];
  __shared__ float red[4];
  __shared__ float scs;
  const float2* x2 = (const float2*)(inp + row * DIMM);
  float2 v = x2[threadIdx.x];
  float s = v.x * v.x + v.y * v.y;
  s = wave_sum(s);
  int lane = threadIdx.x & 63, wid = threadIdx.x >> 6;
  if (lane == 0) red[wid] = s;
  __syncthreads();
  if (threadIdx.x == 0)
    scs = rsqrtf((red[0] + red[1] + red[2] + red[3]) / (float)DIMM + FEPS);
  __syncthreads();
  float scale = scs;
  float2 gg = ((const float2*)g)[threadIdx.x];
  float2 o; o.x = v.x * scale * gg.x; o.y = v.y * scale * gg.y;
  ((float2*)(xn + row * DIMM))[threadIdx.x] = o;
  xs[2 * threadIdx.x] = o.x; xs[2 * threadIdx.x + 1] = o.y;
  __syncthreads();
  int tid = threadIdx.x;
  if (tid < 192) {                       // 24 gate outputs x 8 k-pieces
    int j = tid >> 3, piece = tid & 7;
    const float* xr = xs + piece * 64;
    const float* wr = wg + piece * 64 * 24 + j;
    float sg = 0.f;
#pragma unroll
    for (int kk = 0; kk < 64; ++kk) sg += xr[kk] * wr[kk * 24];
    sg += __shfl_xor(sg, 1); sg += __shfl_xor(sg, 2); sg += __shfl_xor(sg, 4);
    if (piece == 0) gate[row * 24 + j] = 1.0f / (1.0f + expf(-(sg + bg[j])));
  }
}

// ---------------- QKV GEMM: 64x64 tile (384 blocks), scatter epilogue ----------------
__global__ __launch_bounds__(256) void k_gemmA(const float* __restrict__ A,
                                               const float* __restrict__ W,
                                               float* __restrict__ Cout) {
  __shared__ float As[16][64];
  __shared__ float Ws[16][64];
  const int m0 = blockIdx.y * 64, n0 = blockIdx.x * 64;
  const int tid = threadIdx.x, tx = tid & 15, ty = tid >> 4;
  float acc[4][4] = {};
  for (int k0 = 0; k0 < DIMM; k0 += 16) {
    int r = tid >> 2, c4 = (tid & 3) << 2;
    float4 av = *(const float4*)(A + (m0 + r) * DIMM + k0 + c4);
    As[c4 + 0][r] = av.x; As[c4 + 1][r] = av.y;
    As[c4 + 2][r] = av.z; As[c4 + 3][r] = av.w;
    int wr = tid >> 4, wc = (tid & 15) << 2;
    *(float4*)&Ws[wr][wc] = *(const float4*)(W + (k0 + wr) * (3 * DIMM) + n0 + wc);
    __syncthreads();
#pragma unroll
    for (int kk = 0; kk < 16; ++kk) {
      float4 a = *(const float4*)&As[kk][ty << 2];
      float4 w = *(const float4*)&Ws[kk][tx << 2];
      acc[0][0] += a.x * w.x; acc[0][1] += a.x * w.y; acc[0][2] += a.x * w.z; acc[0][3] += a.x * w.w;
      acc[1][0] += a.y * w.x; acc[1][1] += a.y * w.y; acc[1][2] += a.y * w.z; acc[1][3] += a.y * w.w;
      acc[2][0] += a.z * w.x; acc[2][1] += a.z * w.y; acc[2][2] += a.z * w.z; acc[2][3] += a.z * w.w;
      acc[3][0] += a.w * w.x; acc[3][1] += a.w * w.y; acc[3][2] += a.w * w.z; acc[3][3] += a.w * w.w;
    }
    __syncthreads();
  }
#pragma unroll
  for (int ii = 0; ii < 4; ++ii) {
#pragma unroll
    for (int jj = 0; jj < 4; ++jj) {
      int row = m0 + (ty << 2) + ii, col = n0 + (tx << 2) + jj;
      int sec = col >> 9, rem = col & 511, hh = rem >> 6, dd = rem & 63;
      Cout[sec * (H * NSEQ * D) + ((hh * NSEQ) + row) * D + dd] = acc[ii][jj];
    }
  }
}

// ---------------- out-proj GEMM: 64x32 tile, 256 blocks (full CU coverage) ----------------
__global__ __launch_bounds__(256) void k_gemmB(const float* __restrict__ A,
                                               const float* __restrict__ W,
                                               float* __restrict__ Cout) {
  __shared__ float As[16][64];
  __shared__ float Ws[16][32];
  const int m0 = blockIdx.y * 64, n0 = blockIdx.x * 32;
  const int tid = threadIdx.x, tx = tid & 7, ty = tid >> 3;
  float acc[2][4] = {};
  for (int k0 = 0; k0 < DIMM; k0 += 16) {
    int r = tid >> 2, c4 = (tid & 3) << 2;
    float4 av = *(const float4*)(A + (m0 + r) * DIMM + k0 + c4);
    As[c4 + 0][r] = av.x; As[c4 + 1][r] = av.y;
    As[c4 + 2][r] = av.z; As[c4 + 3][r] = av.w;
    int wr = tid >> 4, wc = (tid & 15) << 1;
    *(float2*)&Ws[wr][wc] = *(const float2*)(W + (k0 + wr) * DIMM + n0 + wc);
    __syncthreads();
#pragma unroll
    for (int kk = 0; kk < 16; ++kk) {
      float2 a = *(const float2*)&As[kk][ty << 1];
      float4 w = *(const float4*)&Ws[kk][tx << 2];
      acc[0][0] += a.x * w.x; acc[0][1] += a.x * w.y; acc[0][2] += a.x * w.z; acc[0][3] += a.x * w.w;
      acc[1][0] += a.y * w.x; acc[1][1] += a.y * w.y; acc[1][2] += a.y * w.z; acc[1][3] += a.y * w.w;
    }
    __syncthreads();
  }
#pragma unroll
  for (int ii = 0; ii < 2; ++ii)
#pragma unroll
    for (int jj = 0; jj < 4; ++jj)
      Cout[(m0 + (ty << 1) + ii) * DIMM + n0 + (tx << 2) + jj] = acc[ii][jj];
}

// ---------------- rotary (inline trig) + f16 K/Q/V packing ----------------
#define LOG2_THETA 13.287712379549449f
__global__ __launch_bounds__(256) void k_rot(const float* __restrict__ q, const float* __restrict__ k,
                                             const float* __restrict__ v,
                                             f16* __restrict__ fqh, f16* __restrict__ fkh,
                                             f16* __restrict__ sqh, f16* __restrict__ skh,
                                             f16* __restrict__ vh) {
  int sub = threadIdx.x >> 6, t = threadIdx.x & 63;
  int b = (blockIdx.x << 2) | sub;  // h*1024 + i
  int i = b & (NSEQ - 1);
  int base = b * D + t;
  float qv = q[base], kv = k[base];
  float fr = (float)i * exp2f(-(float)(t & 31) * (LOG2_THETA / 32.0f));
  float sv, cvl; sincosf(fr, &sv, &cvl);
  float2 c2 = make_float2(cvl, sv);
  float2 c1 = make_float2(__shfl(cvl, t >> 1), __shfl(sv, t >> 1));
  float pq1 = __shfl_xor(qv, 1), pk1 = __shfl_xor(kv, 1);
  float xq1 = (t & 1) ? pq1 : -pq1, xk1 = (t & 1) ? pk1 : -pk1;
  fqh[base] = (f16)(qv * c1.x + xq1 * c1.y);
  fkh[base] = (f16)(kv * c1.x + xk1 * c1.y);
  float pq2 = __shfl_xor(qv, 32), pk2 = __shfl_xor(kv, 32);
  float xq2 = (t & 32) ? pq2 : -pq2, xk2 = (t & 32) ? pk2 : -pk2;
  sqh[base] = (f16)(qv * c2.x + xq2 * c2.y);
  skh[base] = (f16)(kv * c2.x + xk2 * c2.y);
  vh[base] = (f16)v[base];
}

// ---------------- compressed K/V conv + mem_kv fill (blk>=512) ----------------
__global__ __launch_bounds__(256) void k_compkv(const float* __restrict__ k, const float* __restrict__ v,
                                                const float* __restrict__ kpos, const float* __restrict__ vpos,
                                                const float* __restrict__ wk, const float* __restrict__ bk,
                                                const float* __restrict__ wv, const float* __restrict__ bv,
                                                const float* __restrict__ mem,
                                                float* __restrict__ ck, float* __restrict__ cv) {
  int blk = blockIdx.x;            // h*64 + w*2 + isV  (or 512+h: mem fill)
  if (blk >= 512) {
    int hh = blk - 512, tid = threadIdx.x;
    int mm = tid >> 6, dd = tid & 63;   // 4 rows x 64 dims
    ck[(hh * 36 + mm) * D + dd] = mem[(hh * 4 + mm) * D + dd];
    cv[(hh * 36 + mm) * D + dd] = mem[H * 4 * D + (hh * 4 + mm) * D + dd];
    return;
  }
  int h = blk >> 6, rem = blk & 63, w = rem >> 1;
  bool isV = rem & 1;
  __shared__ float tileT[64][36];  // [dd][p], padded rows keep 16B alignment
  __shared__ float partial[4][64];
  int tid = threadIdx.x;
  const float* src = isV ? v : k;
  const float* pos = isV ? vpos : kpos;
  for (int e = tid; e < 2048; e += 256) {
    int p = e >> 6, dd = e & 63;
    tileT[dd][p] = src[((h << 10) + (w * 32 + p)) * D + dd] + pos[(h * 32 + p) * D + dd];
  }
  __syncthreads();
  int o = tid & 63, qq = tid >> 6;
  const float4* wm4 = (const float4*)((isV ? wv : wk) + (h * 64 + o) * 2048) + qq * 128;
  float s0 = 0.f, s1 = 0.f, s2 = 0.f, s3 = 0.f;
  for (int ii = 0; ii < 16; ++ii) {
    int iig = qq * 16 + ii;
    const float4* tc = (const float4*)&tileT[iig][0];   // broadcast reads
#pragma unroll
    for (int p4 = 0; p4 < 8; ++p4) {
      float4 tv = tc[p4];
      float4 w4 = wm4[ii * 8 + p4];
      s0 += tv.x * w4.x; s1 += tv.y * w4.y; s2 += tv.z * w4.z; s3 += tv.w * w4.w;
    }
  }
  partial[qq][o] = s0 + s1 + s2 + s3;
  __syncthreads();
  if (tid < 64) {
    float r = (isV ? bv : bk)[h * 64 + tid] +
              partial[0][tid] + partial[1][tid] + partial[2][tid] + partial[3][tid];
    (isV ? cv : ck)[((h * 36) + 4 + w) * D + tid] = r;
  }
}

// ---------------- fused attention: 4 queries per 256-thread block (1 per wave).
// R19 body, launch_bounds(256,6): 6 blocks/CU cap (target 42 VGPR >= natural 40
// -> no clamp/spill), occupancy 45% -> ~70%. ----------------
__global__ __launch_bounds__(256, 6) void k_attn(
    const float* __restrict__ q, const float* __restrict__ ck, const float* __restrict__ cv,
    const f16* __restrict__ fqh, const f16* __restrict__ fkh,
    const f16* __restrict__ sqh, const f16* __restrict__ skh,
    const f16* __restrict__ vh,
    const float* __restrict__ gate, float* __restrict__ pre) {
  int wid = threadIdx.x >> 6;
  int t = threadIdx.x & 63;
  // XCD swizzle (8 XCDs, 2048 blocks, bijective): XCD (blk&7) -> contiguous range
  int blk = ((int)blockIdx.x & 7) * 256 + ((int)blockIdx.x >> 3);
  int b = (blk << 2) | wid;             // h*1024 + i
  int h = b >> 10, i = b & 1023;

  // flat per-wave LDS partition, PRIVATE per phase
  __shared__ __align__(16) char smem[4 * 2560];
  char* sw = smem + wid * 2560;
  float4* qsA  = (float4*)sw;            // 256 B  (phase 1 q, f32)
  uint4* qsuB  = (uint4*)(sw + 256);     // 128 B  (phase 2 fq, packed f16)
  uint4* qsuC  = (uint4*)(sw + 384);     // 128 B  (phase 3 sq, packed f16)
  float* wgt   = (float*)(sw + 512);     // 144 B
  float* ww1   = (float*)(sw + 656);     // 144 B  (phase 1 raw dots)
  float* ww2   = (float*)(sw + 800);     // 1152 B (phase 2 scores)
  float* ww3   = (float*)(sw + 1952);    // 512 B  (phase 3 scores) -> 2464

  int gq = t >> 4, ds = t & 15;
  int seg = t & 7, kloc = t >> 3;      // 8-lane row cooperation

  // hoist all Q loads: independent, can overlap everything
  if (t < 16) qsA[t] = ((const float4*)(q + b * D))[t];
  if (t < 8) {
    qsuB[t] = ((const uint4*)(fqh + b * D))[t];
    qsuC[t] = ((const uint4*)(sqh + b * D))[t];
  }

  // ===== phase 1: compressed attention (f32, exact topk path) =====
  {
    int seg16 = t & 15, rloc = t >> 4;
    const float4* ckb = (const float4*)(ck + h * 36 * D);
#pragma unroll 3
    for (int pass = 0; pass < 9; ++pass) {
      int r = (pass << 2) + rloc;      // 0..35
      float4 kk = ckb[r * 16 + seg16];
      float4 qq = qsA[seg16];
      float a = qq.x * kk.x + qq.y * kk.y + qq.z * kk.z + qq.w * kk.w;
      a += __shfl_xor(a, 1); a += __shfl_xor(a, 2);
      a += __shfl_xor(a, 4); a += __shfl_xor(a, 8);
      if (seg16 == 0) ww1[r] = a;      // raw dot scratch
    }
  }
  float sc = NEGINF;
  if (t < 36) {
    bool vis = (t < 4) || ((t - 4) * 32 + 31 < i);
    sc = vis ? ww1[t] * SCALE : NEGINF;
  }
  float m = wave_max(sc);
  float e = __expf(sc - m);
  float Z = wave_sum(e);
  float myw = (t < 36) ? (e / Z) : -1.0f;
  if (t < 36) wgt[t] = myw;

  // rank-based top-8 (value desc, index asc) — 31 independent shuffles
  float cand = __shfl(myw, t + 4);      // lane t (t<32) holds candidate block t = wgt[4+t]
  cand = (t < 32) ? cand : -1.0f;
  int rank = 0;
#pragma unroll
  for (int o = 1; o < 32; ++o) {
    float ov = __shfl_xor(cand, o);
    int oi = t ^ o;
    rank += (ov > cand || (ov == cand && oi < t)) ? 1 : 0;
  }
  // pack sel/ok into two 32-bit regs: byte r = blk(6b) | ok<<7 (ranks 0-3 -> lo, 4-7 -> hi)
  unsigned fldme = (unsigned)t | ((cand > 1e-10f) ? 0x80u : 0u);
  unsigned selLo = (t < 32 && rank < 4) ? (fldme << (rank << 3)) : 0u;
  unsigned selHi = (t < 32 && rank >= 4 && rank < 8) ? (fldme << ((rank - 4) << 3)) : 0u;
#pragma unroll
  for (int off = 1; off < 64; off <<= 1) {
    selLo |= __shfl_xor((int)selLo, off);
    selHi |= __shfl_xor((int)selHi, off);
  }

  float4 racc = {0.f, 0.f, 0.f, 0.f};
  {
    const float4* cv4 = (const float4*)(cv + h * 36 * D);
#pragma unroll 2
    for (int j = gq; j < 36; j += 4) {
      float wj = wgt[j]; float4 vv = cv4[j * 16 + ds];
      racc.x += wj * vv.x; racc.y += wj * vv.y; racc.z += wj * vv.z; racc.w += wj * vv.w;
    }
  }
#pragma unroll
  for (int off = 16; off <= 32; off <<= 1) {
    racc.x += __shfl_xor(racc.x, off); racc.y += __shfl_xor(racc.y, off);
    racc.z += __shfl_xor(racc.z, off); racc.w += __shfl_xor(racc.w, off);
  }
  float4 result;
  {
    float g0 = gate[i * 24 + h * 3 + 0];
    result.x = g0 * racc.x; result.y = g0 * racc.y;
    result.z = g0 * racc.z; result.w = g0 * racc.w;
  }

  // ===== phase 2: fine attention (f16 K dot2, f16 V), coalesced, register keys =====
  float lmax = NEGINF;
  int ownb = i >> 5;
#pragma unroll 3
  for (int si = 0; si < 9; ++si) {
    int blkidx; bool okg;
    if (si < 8) {
      unsigned fld = (((si & 4) ? selHi : selLo) >> ((si & 3) << 3)) & 0xffu;
      blkidx = (int)(fld & 63u); okg = (fld & 0x80u) != 0u;
    } else { blkidx = ownb; okg = true; }
    const uint4* rowbase = (const uint4*)(fkh + ((h << 10) + (blkidx << 5)) * D);
#pragma unroll
    for (int pass = 0; pass < 4; ++pass) {
      int p = (pass << 3) + kloc;      // key within 32-group
      uint4 kk = rowbase[p * 8 + seg];
      uint4 qq = qsuB[seg];
      float a = 0.f;
      a = FDOT2(as_h2(kk.x), as_h2(qq.x), a);
      a = FDOT2(as_h2(kk.y), as_h2(qq.y), a);
      a = FDOT2(as_h2(kk.z), as_h2(qq.z), a);
      a = FDOT2(as_h2(kk.w), as_h2(qq.w), a);
      a += __shfl_xor(a, 1); a += __shfl_xor(a, 2); a += __shfl_xor(a, 4);
      bool ok = okg && (si < 8 || p <= (i & 31));
      float scf = ok ? a * SCALE : NEGINF;
      if (seg == 0) ww2[(si << 5) + p] = scf;
      lmax = fmaxf(lmax, scf);
    }
  }
  lmax = wave_max(lmax);
  float lsum = 0.f;
#pragma unroll
  for (int rep = 0; rep < 5; ++rep) {
    int s = t + rep * 64;
    if (s < 288) { float e2 = __expf(ww2[s] - lmax); ww2[s] = e2; lsum += e2; }
  }
  float Zf = wave_sum(lsum);
  float4 facc = {0.f, 0.f, 0.f, 0.f};
  {
    const uint2* v2 = (const uint2*)(vh + (h << 10) * D);
    int ownb32 = ownb << 5;
#pragma unroll 3
    for (int si = 0; si < 9; ++si) {
      int kb;
      if (si < 8) {
        unsigned fld = (((si & 4) ? selHi : selLo) >> ((si & 3) << 3)) & 0xffu;
        kb = (int)(fld & 63u) << 5;
      } else kb = ownb32;
      const uint2* vbase = v2 + (kb + gq) * 16 + ds;
      const float* wwb = ww2 + (si << 5) + gq;
#pragma unroll 4
      for (int p = 0; p < 8; ++p) {
        float wj = wwb[p * 4];
        uint2 vv = vbase[p * 64];
        h2 va = as_h2(vv.x), vb2 = as_h2(vv.y);
        facc.x += wj * (float)va.x;  facc.y += wj * (float)va.y;
        facc.z += wj * (float)vb2.x; facc.w += wj * (float)vb2.y;
      }
    }
  }
#pragma unroll
  for (int off = 16; off <= 32; off <<= 1) {
    facc.x += __shfl_xor(facc.x, off); facc.y += __shfl_xor(facc.y, off);
    facc.z += __shfl_xor(facc.z, off); facc.w += __shfl_xor(facc.w, off);
  }
  {
    float gf = gate[i * 24 + h * 3 + 1] / Zf;
    result.x += gf * facc.x; result.y += gf * facc.y;
    result.z += gf * facc.z; result.w += gf * facc.w;
  }

  // ===== phase 3: sliding window (f16 K dot2, f16 V), coalesced =====
  int tb = i >> 6, iq = i & 63;
  int kb0 = tb * 64 - 64;
  float lmax3 = NEGINF;
  {
    const uint4* rb0 = (const uint4*)(skh + ((h << 10) + kb0) * D);     // prev block (invalid if tb==0)
    const uint4* rb1 = (const uint4*)(skh + ((h << 10) + tb * 64) * D); // own block
#pragma unroll 4
    for (int pass = 0; pass < 8; ++pass) {
      int p = (pass << 3) + kloc;      // 0..63
      float sA = NEGINF;
      if (tb > 0 && p >= iq) {         // group-uniform guard: no OOB, min traffic
        uint4 kk = rb0[p * 8 + seg];
        uint4 qq = qsuC[seg];
        float a = 0.f;
        a = FDOT2(as_h2(kk.x), as_h2(qq.x), a);
        a = FDOT2(as_h2(kk.y), as_h2(qq.y), a);
        a = FDOT2(as_h2(kk.z), as_h2(qq.z), a);
        a = FDOT2(as_h2(kk.w), as_h2(qq.w), a);
        a += __shfl_xor(a, 1); a += __shfl_xor(a, 2); a += __shfl_xor(a, 4);
        sA = a * SCALE;
      }
      float sB = NEGINF;
      if (p <= iq) {
        uint4 kk = rb1[p * 8 + seg];
        uint4 qq = qsuC[seg];
        float a = 0.f;
        a = FDOT2(as_h2(kk.x), as_h2(qq.x), a);
        a = FDOT2(as_h2(kk.y), as_h2(qq.y), a);
        a = FDOT2(as_h2(kk.z), as_h2(qq.z), a);
        a = FDOT2(as_h2(kk.w), as_h2(qq.w), a);
        a += __shfl_xor(a, 1); a += __shfl_xor(a, 2); a += __shfl_xor(a, 4);
        sB = a * SCALE;
      }
      if (seg == 0) { ww3[p] = sA; ww3[64 + p] = sB; }
      lmax3 = fmaxf(lmax3, fmaxf(sA, sB));
    }
  }
  float lm = wave_max(lmax3);
  float e0 = __expf(ww3[t] - lm), e1 = __expf(ww3[t + 64] - lm);
  float Zs = wave_sum(e0 + e1);
  ww3[t] = e0; ww3[t + 64] = e1;
  float4 sacc = {0.f, 0.f, 0.f, 0.f};
  {
    const uint2* v2 = (const uint2*)(vh + ((h << 10) + kb0) * D);
#pragma unroll 2
    for (int j = gq; j < 128; j += 4) {
      float wj = ww3[j];
      if (wj != 0.f) {
        uint2 vv = v2[j * 16 + ds];
        h2 va = as_h2(vv.x), vb2 = as_h2(vv.y);
        sacc.x += wj * (float)va.x;  sacc.y += wj * (float)va.y;
        sacc.z += wj * (float)vb2.x; sacc.w += wj * (float)vb2.y;
      }
    }
  }
#pragma unroll
  for (int off = 16; off <= 32; off <<= 1) {
    sacc.x += __shfl_xor(sacc.x, off); sacc.y += __shfl_xor(sacc.y, off);
    sacc.z += __shfl_xor(sacc.z, off); sacc.w += __shfl_xor(sacc.w, off);
  }
  {
    float gs = gate[i * 24 + h * 3 + 2] / Zs;
    result.x += gs * sacc.x; result.y += gs * sacc.y;
    result.z += gs * sacc.z; result.w += gs * sacc.w;
  }

  if (t < 16) ((float4*)(pre + i * DIMM + h * D))[t] = result;
}

extern "C" void kernel_launch(void* const* d_in, const int* in_sizes, int n_in,
                              void* d_out, int out_size, void* d_ws, size_t ws_size,
                              hipStream_t stream) {
  const float* inp    = (const float*)d_in[0];
  const float* g_rms  = (const float*)d_in[1];
  const float* w_qkv  = (const float*)d_in[2];
  const float* mem_kv = (const float*)d_in[3];
  const float* k_pos  = (const float*)d_in[4];
  const float* v_pos  = (const float*)d_in[5];
  const float* wk     = (const float*)d_in[6];
  const float* bk     = (const float*)d_in[7];
  const float* wv     = (const float*)d_in[8];
  const float* bv     = (const float*)d_in[9];
  const float* w_gate = (const float*)d_in[10];
  const float* b_gate = (const float*)d_in[11];
  const float* w_out  = (const float*)d_in[12];
  float* ws  = (float*)d_ws;
  float* out = (float*)d_out;

  float* xn   = ws + OFF_XN;
  float* q    = ws + OFF_Q;
  float* k    = ws + OFF_K;
  float* v    = ws + OFF_V;
  f16* fqh = (f16*)(ws + OFF_FQ);
  f16* fkh = (f16*)(ws + OFF_FKB);
  f16* skh = (f16*)(ws + OFF_SKB);
  f16* sqh = (f16*)(ws + OFF_SQ);
  f16* vh  = (f16*)(ws + OFF_VB);
  float* gate = ws + OFF_GATE;
  float* ck   = ws + OFF_CK;
  float* cv   = ws + OFF_CV;
  float* pre  = ws + OFF_PRE;

  k_rmsnorm<<<NSEQ, 256, 0, stream>>>(inp, g_rms, w_gate, b_gate, xn, gate);
  k_gemmA<<<dim3(24, 16), 256, 0, stream>>>(xn, w_qkv, q);
  k_rot<<<H * NSEQ / 4, 256, 0, stream>>>(q, k, v, fqh, fkh, sqh, skh, vh);
  k_compkv<<<H * 64 + 8, 256, 0, stream>>>(k, v, k_pos, v_pos, wk, bk, wv, bv, mem_kv, ck, cv);
  k_attn<<<H * NSEQ / 4, 256, 0, stream>>>(q, ck, cv, fqh, fkh, sqh, skh, vh, gate, pre);
  k_gemmB<<<dim3(16, 16), 256, 0, stream>>>(pre, w_out, out);
}

// Round 21
// 157.324 us; speedup vs baseline: 1.1499x; 1.1499x over previous
//
#include <hip/hip_runtime.h>
#include <hip/hip_bf16.h>
#include <math.h>

#define H 8
#define NSEQ 1024
#define D 64
#define DIMM 512
#define NSELK 8
#define SCALE 0.125f
#define FEPS 1.1920929e-07f
#define NEGINF (-__builtin_inff())

typedef _Float16 f16;
typedef _Float16 h2 __attribute__((ext_vector_type(2)));
__device__ __forceinline__ h2 as_h2(unsigned u) { return __builtin_bit_cast(h2, u); }

#if __has_builtin(__builtin_amdgcn_fdot2)
#define FDOT2(a, b, c) __builtin_amdgcn_fdot2((a), (b), (c), false)
#else
#define FDOT2(a, b, c) ((c) + (float)(a).x * (float)(b).x + (float)(a).y * (float)(b).y)
#endif

// ws offsets (in floats)
#define OFF_XN    0
#define OFF_Q     524288
#define OFF_K     1048576
#define OFF_V     1572864
#define OFF_FQ    2097152   // f16
#define OFF_FKB   2621440   // f16
#define OFF_SKB   2883584   // f16
#define OFF_SQ    3145728   // f16
#define OFF_VB    3670016   // f16
#define OFF_GATE  4194304
#define OFF_CK    4218880
#define OFF_CV    4237312
#define OFF_PRE   4255744

__device__ __forceinline__ float wave_max(float v) {
#pragma unroll
  for (int off = 32; off > 0; off >>= 1) v = fmaxf(v, __shfl_xor(v, off));
  return v;
}
__device__ __forceinline__ float wave_sum(float v) {
#pragma unroll
  for (int off = 32; off > 0; off >>= 1) v += __shfl_xor(v, off);
  return v;
}

// ---------------- RMSNorm + fused gate projection ----------------
__global__ __launch_bounds__(256) void k_rmsnorm(const float* __restrict__ inp,
                                                 const float* __restrict__ g,
                                                 const float* __restrict__ wg,
                                                 const float* __restrict__ bg,
                                                 float* __restrict__ xn,
                                                 float* __restrict__ gate) {
  int row = blockIdx.x;
  __shared__ float xs[512];
  __shared__ float red[4];
  __shared__ float scs;
  const float2* x2 = (const float2*)(inp + row * DIMM);
  float2 v = x2[threadIdx.x];
  float s = v.x * v.x + v.y * v.y;
  s = wave_sum(s);
  int lane = threadIdx.x & 63, wid = threadIdx.x >> 6;
  if (lane == 0) red[wid] = s;
  __syncthreads();
  if (threadIdx.x == 0)
    scs = rsqrtf((red[0] + red[1] + red[2] + red[3]) / (float)DIMM + FEPS);
  __syncthreads();
  float scale = scs;
  float2 gg = ((const float2*)g)[threadIdx.x];
  float2 o; o.x = v.x * scale * gg.x; o.y = v.y * scale * gg.y;
  ((float2*)(xn + row * DIMM))[threadIdx.x] = o;
  xs[2 * threadIdx.x] = o.x; xs[2 * threadIdx.x + 1] = o.y;
  __syncthreads();
  int tid = threadIdx.x;
  if (tid < 192) {                       // 24 gate outputs x 8 k-pieces
    int j = tid >> 3, piece = tid & 7;
    const float* xr = xs + piece * 64;
    const float* wr = wg + piece * 64 * 24 + j;
    float sg = 0.f;
#pragma unroll
    for (int kk = 0; kk < 64; ++kk) sg += xr[kk] * wr[kk * 24];
    sg += __shfl_xor(sg, 1); sg += __shfl_xor(sg, 2); sg += __shfl_xor(sg, 4);
    if (piece == 0) gate[row * 24 + j] = 1.0f / (1.0f + expf(-(sg + bg[j])));
  }
}

// ---------------- QKV GEMM: 64x64 tile (384 blocks), scatter epilogue ----------------
__global__ __launch_bounds__(256) void k_gemmA(const float* __restrict__ A,
                                               const float* __restrict__ W,
                                               float* __restrict__ Cout) {
  __shared__ float As[16][64];
  __shared__ float Ws[16][64];
  const int m0 = blockIdx.y * 64, n0 = blockIdx.x * 64;
  const int tid = threadIdx.x, tx = tid & 15, ty = tid >> 4;
  float acc[4][4] = {};
  for (int k0 = 0; k0 < DIMM; k0 += 16) {
    int r = tid >> 2, c4 = (tid & 3) << 2;
    float4 av = *(const float4*)(A + (m0 + r) * DIMM + k0 + c4);
    As[c4 + 0][r] = av.x; As[c4 + 1][r] = av.y;
    As[c4 + 2][r] = av.z; As[c4 + 3][r] = av.w;
    int wr = tid >> 4, wc = (tid & 15) << 2;
    *(float4*)&Ws[wr][wc] = *(const float4*)(W + (k0 + wr) * (3 * DIMM) + n0 + wc);
    __syncthreads();
#pragma unroll
    for (int kk = 0; kk < 16; ++kk) {
      float4 a = *(const float4*)&As[kk][ty << 2];
      float4 w = *(const float4*)&Ws[kk][tx << 2];
      acc[0][0] += a.x * w.x; acc[0][1] += a.x * w.y; acc[0][2] += a.x * w.z; acc[0][3] += a.x * w.w;
      acc[1][0] += a.y * w.x; acc[1][1] += a.y * w.y; acc[1][2] += a.y * w.z; acc[1][3] += a.y * w.w;
      acc[2][0] += a.z * w.x; acc[2][1] += a.z * w.y; acc[2][2] += a.z * w.z; acc[2][3] += a.z * w.w;
      acc[3][0] += a.w * w.x; acc[3][1] += a.w * w.y; acc[3][2] += a.w * w.z; acc[3][3] += a.w * w.w;
    }
    __syncthreads();
  }
#pragma unroll
  for (int ii = 0; ii < 4; ++ii) {
#pragma unroll
    for (int jj = 0; jj < 4; ++jj) {
      int row = m0 + (ty << 2) + ii, col = n0 + (tx << 2) + jj;
      int sec = col >> 9, rem = col & 511, hh = rem >> 6, dd = rem & 63;
      Cout[sec * (H * NSEQ * D) + ((hh * NSEQ) + row) * D + dd] = acc[ii][jj];
    }
  }
}

// ---------------- out-proj GEMM: 64x32 tile, 256 blocks (full CU coverage) ----------------
__global__ __launch_bounds__(256) void k_gemmB(const float* __restrict__ A,
                                               const float* __restrict__ W,
                                               float* __restrict__ Cout) {
  __shared__ float As[16][64];
  __shared__ float Ws[16][32];
  const int m0 = blockIdx.y * 64, n0 = blockIdx.x * 32;
  const int tid = threadIdx.x, tx = tid & 7, ty = tid >> 3;
  float acc[2][4] = {};
  for (int k0 = 0; k0 < DIMM; k0 += 16) {
    int r = tid >> 2, c4 = (tid & 3) << 2;
    float4 av = *(const float4*)(A + (m0 + r) * DIMM + k0 + c4);
    As[c4 + 0][r] = av.x; As[c4 + 1][r] = av.y;
    As[c4 + 2][r] = av.z; As[c4 + 3][r] = av.w;
    int wr = tid >> 4, wc = (tid & 15) << 1;
    *(float2*)&Ws[wr][wc] = *(const float2*)(W + (k0 + wr) * DIMM + n0 + wc);
    __syncthreads();
#pragma unroll
    for (int kk = 0; kk < 16; ++kk) {
      float2 a = *(const float2*)&As[kk][ty << 1];
      float4 w = *(const float4*)&Ws[kk][tx << 2];
      acc[0][0] += a.x * w.x; acc[0][1] += a.x * w.y; acc[0][2] += a.x * w.z; acc[0][3] += a.x * w.w;
      acc[1][0] += a.y * w.x; acc[1][1] += a.y * w.y; acc[1][2] += a.y * w.z; acc[1][3] += a.y * w.w;
    }
    __syncthreads();
  }
#pragma unroll
  for (int ii = 0; ii < 2; ++ii)
#pragma unroll
    for (int jj = 0; jj < 4; ++jj)
      Cout[(m0 + (ty << 1) + ii) * DIMM + n0 + (tx << 2) + jj] = acc[ii][jj];
}

// ---------------- rotary (inline trig) + f16 K/Q/V packing ----------------
#define LOG2_THETA 13.287712379549449f
__global__ __launch_bounds__(256) void k_rot(const float* __restrict__ q, const float* __restrict__ k,
                                             const float* __restrict__ v,
                                             f16* __restrict__ fqh, f16* __restrict__ fkh,
                                             f16* __restrict__ sqh, f16* __restrict__ skh,
                                             f16* __restrict__ vh) {
  int sub = threadIdx.x >> 6, t = threadIdx.x & 63;
  int b = (blockIdx.x << 2) | sub;  // h*1024 + i
  int i = b & (NSEQ - 1);
  int base = b * D + t;
  float qv = q[base], kv = k[base];
  float fr = (float)i * exp2f(-(float)(t & 31) * (LOG2_THETA / 32.0f));
  float sv, cvl; sincosf(fr, &sv, &cvl);
  float2 c2 = make_float2(cvl, sv);
  float2 c1 = make_float2(__shfl(cvl, t >> 1), __shfl(sv, t >> 1));
  float pq1 = __shfl_xor(qv, 1), pk1 = __shfl_xor(kv, 1);
  float xq1 = (t & 1) ? pq1 : -pq1, xk1 = (t & 1) ? pk1 : -pk1;
  fqh[base] = (f16)(qv * c1.x + xq1 * c1.y);
  fkh[base] = (f16)(kv * c1.x + xk1 * c1.y);
  float pq2 = __shfl_xor(qv, 32), pk2 = __shfl_xor(kv, 32);
  float xq2 = (t & 32) ? pq2 : -pq2, xk2 = (t & 32) ? pk2 : -pk2;
  sqh[base] = (f16)(qv * c2.x + xq2 * c2.y);
  skh[base] = (f16)(kv * c2.x + xk2 * c2.y);
  vh[base] = (f16)v[base];
}

// ---------------- compressed K/V conv + mem_kv fill (blk>=512).
// COALESCED weight reads: seg=tid&7 owns p-quad, og=tid>>3 owns output row ->
// each instruction touches 8 contiguous 128B weight rows (was 64 scattered 8KB-
// strided rows). Full i-range per thread -> no cross-wave partial reduce. ----------------
__global__ __launch_bounds__(256) void k_compkv(const float* __restrict__ k, const float* __restrict__ v,
                                                const float* __restrict__ kpos, const float* __restrict__ vpos,
                                                const float* __restrict__ wk, const float* __restrict__ bk,
                                                const float* __restrict__ wv, const float* __restrict__ bv,
                                                const float* __restrict__ mem,
                                                float* __restrict__ ck, float* __restrict__ cv) {
  int blk = blockIdx.x;            // h*64 + w*2 + isV  (or 512+h: mem fill)
  if (blk >= 512) {
    int hh = blk - 512, tid = threadIdx.x;
    int mm = tid >> 6, dd = tid & 63;   // 4 rows x 64 dims
    ck[(hh * 36 + mm) * D + dd] = mem[(hh * 4 + mm) * D + dd];
    cv[(hh * 36 + mm) * D + dd] = mem[H * 4 * D + (hh * 4 + mm) * D + dd];
    return;
  }
  int h = blk >> 6, rem = blk & 63, w = rem >> 1;
  bool isV = rem & 1;
  __shared__ __align__(16) float tileT[64][36];  // [dd][p], 36-pad keeps float4 rows 16B-aligned (144B)
  int tid = threadIdx.x;
  const float* src = isV ? v : k;
  const float* pos = isV ? vpos : kpos;
  for (int e = tid; e < 2048; e += 256) {
    int p = e >> 6, dd = e & 63;
    tileT[dd][p] = src[((h << 10) + (w * 32 + p)) * D + dd] + pos[(h * 32 + p) * D + dd];
  }
  __syncthreads();
  int seg = tid & 7, og = tid >> 3;    // og 0..31; outputs og and og+32
  const float4* wA = (const float4*)((isV ? wv : wk) + (h * 64 + og) * 2048);
  const float4* wB = wA + 32 * 512;    // +32 output rows (each 2048 floats = 512 float4)
  float accA = 0.f, accB = 0.f;
#pragma unroll 4
  for (int i = 0; i < 64; ++i) {
    float4 tv = *(const float4*)&tileT[i][seg << 2];
    float4 a4 = wA[i * 8 + seg];
    float4 b4 = wB[i * 8 + seg];
    accA += tv.x * a4.x + tv.y * a4.y + tv.z * a4.z + tv.w * a4.w;
    accB += tv.x * b4.x + tv.y * b4.y + tv.z * b4.z + tv.w * b4.w;
  }
  accA += __shfl_xor(accA, 1); accA += __shfl_xor(accA, 2); accA += __shfl_xor(accA, 4);
  accB += __shfl_xor(accB, 1); accB += __shfl_xor(accB, 2); accB += __shfl_xor(accB, 4);
  if (seg == 0) {
    float* dst = (isV ? cv : ck) + ((h * 36) + 4 + w) * D;
    const float* bb = (isV ? bv : bk) + h * 64;
    dst[og] = bb[og] + accA;
    dst[og + 32] = bb[og + 32] + accB;
  }
}

// ---------------- fused attention: 4 queries per 256-thread block (1 per wave).
// R19 proven body: coalesced QK (f16 dot2), register-packed top-8, private
// per-phase LDS, XCD swizzle, launch_bounds(256,4). ----------------
__global__ __launch_bounds__(256, 4) void k_attn(
    const float* __restrict__ q, const float* __restrict__ ck, const float* __restrict__ cv,
    const f16* __restrict__ fqh, const f16* __restrict__ fkh,
    const f16* __restrict__ sqh, const f16* __restrict__ skh,
    const f16* __restrict__ vh,
    const float* __restrict__ gate, float* __restrict__ pre) {
  int wid = threadIdx.x >> 6;
  int t = threadIdx.x & 63;
  // XCD swizzle (8 XCDs, 2048 blocks, bijective): XCD (blk&7) -> contiguous range
  int blk = ((int)blockIdx.x & 7) * 256 + ((int)blockIdx.x >> 3);
  int b = (blk << 2) | wid;             // h*1024 + i
  int h = b >> 10, i = b & 1023;

  // flat per-wave LDS partition, PRIVATE per phase
  __shared__ __align__(16) char smem[4 * 2560];
  char* sw = smem + wid * 2560;
  float4* qsA  = (float4*)sw;            // 256 B  (phase 1 q, f32)
  uint4* qsuB  = (uint4*)(sw + 256);     // 128 B  (phase 2 fq, packed f16)
  uint4* qsuC  = (uint4*)(sw + 384);     // 128 B  (phase 3 sq, packed f16)
  float* wgt   = (float*)(sw + 512);     // 144 B
  float* ww1   = (float*)(sw + 656);     // 144 B  (phase 1 raw dots)
  float* ww2   = (float*)(sw + 800);     // 1152 B (phase 2 scores)
  float* ww3   = (float*)(sw + 1952);    // 512 B  (phase 3 scores) -> 2464

  int gq = t >> 4, ds = t & 15;
  int seg = t & 7, kloc = t >> 3;      // 8-lane row cooperation

  // hoist all Q loads: independent, can overlap everything
  if (t < 16) qsA[t] = ((const float4*)(q + b * D))[t];
  if (t < 8) {
    qsuB[t] = ((const uint4*)(fqh + b * D))[t];
    qsuC[t] = ((const uint4*)(sqh + b * D))[t];
  }

  // ===== phase 1: compressed attention (f32, exact topk path) =====
  {
    int seg16 = t & 15, rloc = t >> 4;
    const float4* ckb = (const float4*)(ck + h * 36 * D);
#pragma unroll 3
    for (int pass = 0; pass < 9; ++pass) {
      int r = (pass << 2) + rloc;      // 0..35
      float4 kk = ckb[r * 16 + seg16];
      float4 qq = qsA[seg16];
      float a = qq.x * kk.x + qq.y * kk.y + qq.z * kk.z + qq.w * kk.w;
      a += __shfl_xor(a, 1); a += __shfl_xor(a, 2);
      a += __shfl_xor(a, 4); a += __shfl_xor(a, 8);
      if (seg16 == 0) ww1[r] = a;      // raw dot scratch
    }
  }
  float sc = NEGINF;
  if (t < 36) {
    bool vis = (t < 4) || ((t - 4) * 32 + 31 < i);
    sc = vis ? ww1[t] * SCALE : NEGINF;
  }
  float m = wave_max(sc);
  float e = __expf(sc - m);
  float Z = wave_sum(e);
  float myw = (t < 36) ? (e / Z) : -1.0f;
  if (t < 36) wgt[t] = myw;

  // rank-based top-8 (value desc, index asc) — 31 independent shuffles
  float cand = __shfl(myw, t + 4);      // lane t (t<32) holds candidate block t = wgt[4+t]
  cand = (t < 32) ? cand : -1.0f;
  int rank = 0;
#pragma unroll
  for (int o = 1; o < 32; ++o) {
    float ov = __shfl_xor(cand, o);
    int oi = t ^ o;
    rank += (ov > cand || (ov == cand && oi < t)) ? 1 : 0;
  }
  // pack sel/ok into two 32-bit regs: byte r = blk(6b) | ok<<7 (ranks 0-3 -> lo, 4-7 -> hi)
  unsigned fldme = (unsigned)t | ((cand > 1e-10f) ? 0x80u : 0u);
  unsigned selLo = (t < 32 && rank < 4) ? (fldme << (rank << 3)) : 0u;
  unsigned selHi = (t < 32 && rank >= 4 && rank < 8) ? (fldme << ((rank - 4) << 3)) : 0u;
#pragma unroll
  for (int off = 1; off < 64; off <<= 1) {
    selLo |= __shfl_xor((int)selLo, off);
    selHi |= __shfl_xor((int)selHi, off);
  }

  float4 racc = {0.f, 0.f, 0.f, 0.f};
  {
    const float4* cv4 = (const float4*)(cv + h * 36 * D);
#pragma unroll 2
    for (int j = gq; j < 36; j += 4) {
      float wj = wgt[j]; float4 vv = cv4[j * 16 + ds];
      racc.x += wj * vv.x; racc.y += wj * vv.y; racc.z += wj * vv.z; racc.w += wj * vv.w;
    }
  }
#pragma unroll
  for (int off = 16; off <= 32; off <<= 1) {
    racc.x += __shfl_xor(racc.x, off); racc.y += __shfl_xor(racc.y, off);
    racc.z += __shfl_xor(racc.z, off); racc.w += __shfl_xor(racc.w, off);
  }
  float4 result;
  {
    float g0 = gate[i * 24 + h * 3 + 0];
    result.x = g0 * racc.x; result.y = g0 * racc.y;
    result.z = g0 * racc.z; result.w = g0 * racc.w;
  }

  // ===== phase 2: fine attention (f16 K dot2, f16 V), coalesced, register keys =====
  float lmax = NEGINF;
  int ownb = i >> 5;
#pragma unroll 3
  for (int si = 0; si < 9; ++si) {
    int blkidx; bool okg;
    if (si < 8) {
      unsigned fld = (((si & 4) ? selHi : selLo) >> ((si & 3) << 3)) & 0xffu;
      blkidx = (int)(fld & 63u); okg = (fld & 0x80u) != 0u;
    } else { blkidx = ownb; okg = true; }
    const uint4* rowbase = (const uint4*)(fkh + ((h << 10) + (blkidx << 5)) * D);
#pragma unroll
    for (int pass = 0; pass < 4; ++pass) {
      int p = (pass << 3) + kloc;      // key within 32-group
      uint4 kk = rowbase[p * 8 + seg];
      uint4 qq = qsuB[seg];
      float a = 0.f;
      a = FDOT2(as_h2(kk.x), as_h2(qq.x), a);
      a = FDOT2(as_h2(kk.y), as_h2(qq.y), a);
      a = FDOT2(as_h2(kk.z), as_h2(qq.z), a);
      a = FDOT2(as_h2(kk.w), as_h2(qq.w), a);
      a += __shfl_xor(a, 1); a += __shfl_xor(a, 2); a += __shfl_xor(a, 4);
      bool ok = okg && (si < 8 || p <= (i & 31));
      float scf = ok ? a * SCALE : NEGINF;
      if (seg == 0) ww2[(si << 5) + p] = scf;
      lmax = fmaxf(lmax, scf);
    }
  }
  lmax = wave_max(lmax);
  float lsum = 0.f;
#pragma unroll
  for (int rep = 0; rep < 5; ++rep) {
    int s = t + rep * 64;
    if (s < 288) { float e2 = __expf(ww2[s] - lmax); ww2[s] = e2; lsum += e2; }
  }
  float Zf = wave_sum(lsum);
  float4 facc = {0.f, 0.f, 0.f, 0.f};
  {
    const uint2* v2 = (const uint2*)(vh + (h << 10) * D);
    int ownb32 = ownb << 5;
#pragma unroll 3
    for (int si = 0; si < 9; ++si) {
      int kb;
      if (si < 8) {
        unsigned fld = (((si & 4) ? selHi : selLo) >> ((si & 3) << 3)) & 0xffu;
        kb = (int)(fld & 63u) << 5;
      } else kb = ownb32;
      const uint2* vbase = v2 + (kb + gq) * 16 + ds;
      const float* wwb = ww2 + (si << 5) + gq;
#pragma unroll 4
      for (int p = 0; p < 8; ++p) {
        float wj = wwb[p * 4];
        uint2 vv = vbase[p * 64];
        h2 va = as_h2(vv.x), vb2 = as_h2(vv.y);
        facc.x += wj * (float)va.x;  facc.y += wj * (float)va.y;
        facc.z += wj * (float)vb2.x; facc.w += wj * (float)vb2.y;
      }
    }
  }
#pragma unroll
  for (int off = 16; off <= 32; off <<= 1) {
    facc.x += __shfl_xor(facc.x, off); facc.y += __shfl_xor(facc.y, off);
    facc.z += __shfl_xor(facc.z, off); facc.w += __shfl_xor(facc.w, off);
  }
  {
    float gf = gate[i * 24 + h * 3 + 1] / Zf;
    result.x += gf * facc.x; result.y += gf * facc.y;
    result.z += gf * facc.z; result.w += gf * facc.w;
  }

  // ===== phase 3: sliding window (f16 K dot2, f16 V), coalesced =====
  int tb = i >> 6, iq = i & 63;
  int kb0 = tb * 64 - 64;
  float lmax3 = NEGINF;
  {
    const uint4* rb0 = (const uint4*)(skh + ((h << 10) + kb0) * D);     // prev block (invalid if tb==0)
    const uint4* rb1 = (const uint4*)(skh + ((h << 10) + tb * 64) * D); // own block
#pragma unroll 4
    for (int pass = 0; pass < 8; ++pass) {
      int p = (pass << 3) + kloc;      // 0..63
      float sA = NEGINF;
      if (tb > 0 && p >= iq) {         // group-uniform guard: no OOB, min traffic
        uint4 kk = rb0[p * 8 + seg];
        uint4 qq = qsuC[seg];
        float a = 0.f;
        a = FDOT2(as_h2(kk.x), as_h2(qq.x), a);
        a = FDOT2(as_h2(kk.y), as_h2(qq.y), a);
        a = FDOT2(as_h2(kk.z), as_h2(qq.z), a);
        a = FDOT2(as_h2(kk.w), as_h2(qq.w), a);
        a += __shfl_xor(a, 1); a += __shfl_xor(a, 2); a += __shfl_xor(a, 4);
        sA = a * SCALE;
      }
      float sB = NEGINF;
      if (p <= iq) {
        uint4 kk = rb1[p * 8 + seg];
        uint4 qq = qsuC[seg];
        float a = 0.f;
        a = FDOT2(as_h2(kk.x), as_h2(qq.x), a);
        a = FDOT2(as_h2(kk.y), as_h2(qq.y), a);
        a = FDOT2(as_h2(kk.z), as_h2(qq.z), a);
        a = FDOT2(as_h2(kk.w), as_h2(qq.w), a);
        a += __shfl_xor(a, 1); a += __shfl_xor(a, 2); a += __shfl_xor(a, 4);
        sB = a * SCALE;
      }
      if (seg == 0) { ww3[p] = sA; ww3[64 + p] = sB; }
      lmax3 = fmaxf(lmax3, fmaxf(sA, sB));
    }
  }
  float lm = wave_max(lmax3);
  float e0 = __expf(ww3[t] - lm), e1 = __expf(ww3[t + 64] - lm);
  float Zs = wave_sum(e0 + e1);
  ww3[t] = e0; ww3[t + 64] = e1;
  float4 sacc = {0.f, 0.f, 0.f, 0.f};
  {
    const uint2* v2 = (const uint2*)(vh + ((h << 10) + kb0) * D);
#pragma unroll 2
    for (int j = gq; j < 128; j += 4) {
      float wj = ww3[j];
      if (wj != 0.f) {
        uint2 vv = v2[j * 16 + ds];
        h2 va = as_h2(vv.x), vb2 = as_h2(vv.y);
        sacc.x += wj * (float)va.x;  sacc.y += wj * (float)va.y;
        sacc.z += wj * (float)vb2.x; sacc.w += wj * (float)vb2.y;
      }
    }
  }
#pragma unroll
  for (int off = 16; off <= 32; off <<= 1) {
    sacc.x += __shfl_xor(sacc.x, off); sacc.y += __shfl_xor(sacc.y, off);
    sacc.z += __shfl_xor(sacc.z, off); sacc.w += __shfl_xor(sacc.w, off);
  }
  {
    float gs = gate[i * 24 + h * 3 + 2] / Zs;
    result.x += gs * sacc.x; result.y += gs * sacc.y;
    result.z += gs * sacc.z; result.w += gs * sacc.w;
  }

  if (t < 16) ((float4*)(pre + i * DIMM + h * D))[t] = result;
}

extern "C" void kernel_launch(void* const* d_in, const int* in_sizes, int n_in,
                              void* d_out, int out_size, void* d_ws, size_t ws_size,
                              hipStream_t stream) {
  const float* inp    = (const float*)d_in[0];
  const float* g_rms  = (const float*)d_in[1];
  const float* w_qkv  = (const float*)d_in[2];
  const float* mem_kv = (const float*)d_in[3];
  const float* k_pos  = (const float*)d_in[4];
  const float* v_pos  = (const float*)d_in[5];
  const float* wk     = (const float*)d_in[6];
  const float* bk     = (const float*)d_in[7];
  const float* wv     = (const float*)d_in[8];
  const float* bv     = (const float*)d_in[9];
  const float* w_gate = (const float*)d_in[10];
  const float* b_gate = (const float*)d_in[11];
  const float* w_out  = (const float*)d_in[12];
  float* ws  = (float*)d_ws;
  float* out = (float*)d_out;

  float* xn   = ws + OFF_XN;
  float* q    = ws + OFF_Q;
  float* k    = ws + OFF_K;
  float* v    = ws + OFF_V;
  f16* fqh = (f16*)(ws + OFF_FQ);
  f16* fkh = (f16*)(ws + OFF_FKB);
  f16* skh = (f16*)(ws + OFF_SKB);
  f16* sqh = (f16*)(ws + OFF_SQ);
  f16* vh  = (f16*)(ws + OFF_VB);
  float* gate = ws + OFF_GATE;
  float* ck   = ws + OFF_CK;
  float* cv   = ws + OFF_CV;
  float* pre  = ws + OFF_PRE;

  k_rmsnorm<<<NSEQ, 256, 0, stream>>>(inp, g_rms, w_gate, b_gate, xn, gate);
  k_gemmA<<<dim3(24, 16), 256, 0, stream>>>(xn, w_qkv, q);
  k_rot<<<H * NSEQ / 4, 256, 0, stream>>>(q, k, v, fqh, fkh, sqh, skh, vh);
  k_compkv<<<H * 64 + 8, 256, 0, stream>>>(k, v, k_pos, v_pos, wk, bk, wv, bv, mem_kv, ck, cv);
  k_attn<<<H * NSEQ / 4, 256, 0, stream>>>(q, ck, cv, fqh, fkh, sqh, skh, vh, gate, pre);
  k_gemmB<<<dim3(16, 16), 256, 0, stream>>>(pre, w_out, out);
}